// Round 9
// baseline (87.402 us; speedup 1.0000x reference)
//
#include <hip/hip_runtime.h>
#include <hip/hip_bf16.h>
#include <cmath>

#define Bn 16
#define Nn 2048
#define Dn 1024
#define Hn 256
#define An 128

typedef __bf16 bf16x8 __attribute__((ext_vector_type(8)));
typedef float f32x4 __attribute__((ext_vector_type(4)));
typedef unsigned short ushort8v __attribute__((ext_vector_type(8)));
typedef unsigned int uint4v __attribute__((ext_vector_type(4)));

// lgkm-only barrier: global streams are never drained at a barrier
#define LDS_BARRIER do {                                   \
    asm volatile("s_waitcnt lgkmcnt(0)" ::: "memory");     \
    __builtin_amdgcn_s_barrier();                          \
    __builtin_amdgcn_sched_barrier(0);                     \
  } while (0)

static __device__ __forceinline__ unsigned short f2bf(float f) {
  unsigned u = __float_as_uint(f);
  u += 0x7fffu + ((u >> 16) & 1u);
  return (unsigned short)(u >> 16);
}

static __device__ __forceinline__ bf16x8 cvt8(const float4 a, const float4 b) {
  bf16x8 r;
  r[0] = (__bf16)a.x; r[1] = (__bf16)a.y; r[2] = (__bf16)a.z; r[3] = (__bf16)a.w;
  r[4] = (__bf16)b.x; r[5] = (__bf16)b.y; r[6] = (__bf16)b.z; r[7] = (__bf16)b.w;
  return r;
}

// ---------------- kernel 0: prepack W1 and Wa1 into swizzled bf16 LDS images --
// W1pack: per k-step kc (BK=32), 1024 slots of 16B. Slot u: col=u>>2, pq=u&3,
//   logical quarter lq = pq ^ ((col>>1)&3); data = W1[col][kc*32+lq*8 .. +8].
// Wa1pack: 4096 slots. Slot v: row=v>>5, ps=v&31, ls = ps ^ (row&7);
//   data = Wa1[row][ls*8 .. +8].
__global__ __launch_bounds__(256) void pack_weights(
    const float* __restrict__ W1, const float* __restrict__ Wa1,
    unsigned short* __restrict__ w1p, unsigned short* __restrict__ wa1p) {
  const int idx = blockIdx.x * 256 + threadIdx.x;
  const float* src;
  unsigned short* dst;
  if (blockIdx.x < 128) {
    const int kc  = idx >> 10;
    const int u   = idx & 1023;
    const int col = u >> 2;
    const int lq  = (u & 3) ^ ((col >> 1) & 3);
    src = W1 + (size_t)col * Dn + (kc << 5) + (lq << 3);
    dst = w1p + (size_t)idx * 8;
  } else {
    const int v   = idx - 32768;
    const int row = v >> 5;
    const int ls  = (v & 31) ^ (row & 7);
    src = Wa1 + (size_t)row * Hn + (ls << 3);
    dst = wa1p + (size_t)v * 8;
  }
  const float4 a = *(const float4*)src;
  const float4 b = *(const float4*)(src + 4);
  ushort8v o;
  o[0] = f2bf(a.x); o[1] = f2bf(a.y); o[2] = f2bf(a.z); o[3] = f2bf(a.w);
  o[4] = f2bf(b.x); o[5] = f2bf(b.y); o[6] = f2bf(b.z); o[7] = f2bf(b.w);
  *(ushort8v*)dst = o;
}

// ---------------- kernel 1: stage1 GEMM + LN + GELU + Wc; h -> global --------
// grid 512 x 256 thr (4 waves). BM=64, BN=256, BK=32, 32 steps.
// Reg-staged A and B (no glds); one lgkm barrier/step; 3 blocks/CU.
// LDS: A dbuf 2x4K [0,8K) | B dbuf 2x16K [8K,40K) | red 2K @40960
// epilogue: h tile 64x512B reuses [8K,40K)
#define K1A(p) ((p) * 4096)
#define K1B(p) (8192 + (p) * 16384)
#define K1H    8192
#define K1RED  40960
__global__ __launch_bounds__(256, 3) void gemm_ln_kernel(
    const float* __restrict__ x,
    const float* __restrict__ b1,
    const float* __restrict__ ln_g,
    const float* __restrict__ ln_b,
    const float* __restrict__ Wc,
    const float* __restrict__ bc,
    const unsigned short* __restrict__ w1p,
    float* __restrict__ scores_out,
    unsigned short* __restrict__ h_out)   // (B*N, 256) bf16 row-major
{
  __shared__ __align__(16) char lds[43008];

  const int tid  = threadIdx.x;
  const int wv   = tid >> 6;
  const int lane = tid & 63;
  const int l15  = lane & 15;
  const int lhi  = lane >> 4;
  const int rg   = wv >> 1;
  const int cw   = wv & 1;

  const int gr0 = blockIdx.x << 6;
  const int bb  = gr0 >> 11;
  const int n0  = gr0 & (Nn - 1);

  f32x4 acc[2][8];
  #pragma unroll
  for (int rf = 0; rf < 2; ++rf)
    #pragma unroll
    for (int cf = 0; cf < 8; ++cf)
      acc[rf][cf] = (f32x4){0.f, 0.f, 0.f, 0.f};

  // A staging: thread -> row tid>>2, quarter aq=tid&3 (8 k's = one 16B slot)
  const int arow = tid >> 2, aq = tid & 3;
  const int aphys = aq ^ ((arow >> 1) & 3);
  const float* xsrc = x + (size_t)(gr0 + arow) * Dn + (aq << 3);
  const int awoff = arow * 64 + (aphys << 4);

  // B staging: contiguous; pack already swizzled
  const unsigned short* bsrc = w1p + (size_t)tid * 8;   // + kc*8192 + q*2048

  // frag read bases (XOR is identical for all rows/cols of a frag set)
  const int bx    = lhi ^ ((l15 >> 1) & 3);
  const int aoff  = ((rg << 5) + l15) * 64 + (bx << 4);        // +1024 for rf=1
  const int boff  = (((cw << 7) + l15) * 64) + (bx << 4);      // +cf*1024

  float4 xs0, xs1;
  uint4v Bst[4];

  auto loadStage = [&](int kc) {
    xs0 = *(const float4*)(xsrc + (kc << 5));
    xs1 = *(const float4*)(xsrc + (kc << 5) + 4);
    const unsigned short* bp = bsrc + (size_t)kc * 8192;
    #pragma unroll
    for (int q = 0; q < 4; ++q)
      Bst[q] = *(const uint4v*)(bp + q * 2048);
  };
  auto writeStage = [&](int p) {
    *(bf16x8*)(lds + K1A(p) + awoff) = cvt8(xs0, xs1);
    #pragma unroll
    for (int q = 0; q < 4; ++q)
      *(uint4v*)(lds + K1B(p) + ((q << 8) + tid) * 16) = Bst[q];
  };
  auto computeStep = [&](int p) {
    const char* Ab = lds + K1A(p);
    const char* Bb = lds + K1B(p);
    __builtin_amdgcn_s_setprio(1);
    const bf16x8 aA = *(const bf16x8*)(Ab + aoff);
    const bf16x8 aB = *(const bf16x8*)(Ab + aoff + 1024);
    #pragma unroll
    for (int cf = 0; cf < 8; ++cf) {
      const bf16x8 bfr = *(const bf16x8*)(Bb + boff + cf * 1024);
      acc[0][cf] = __builtin_amdgcn_mfma_f32_16x16x32_bf16(aA, bfr, acc[0][cf], 0, 0, 0);
      acc[1][cf] = __builtin_amdgcn_mfma_f32_16x16x32_bf16(aB, bfr, acc[1][cf], 0, 0, 0);
    }
    __builtin_amdgcn_s_setprio(0);
  };

  // prologue
  loadStage(0);
  writeStage(0);
  LDS_BARRIER;

  #pragma unroll
  for (int kc = 0; kc < 32; ++kc) {
    const int p = kc & 1;
    if (kc < 31) loadStage(kc + 1);    // global loads: land under compute
    computeStep(p);
    if (kc < 31) {
      writeStage(p ^ 1);               // compiler waits vmcnt per-wave here
      LDS_BARRIER;                     // lgkm only — no vmcnt at barrier
    }
  }
  __syncthreads();   // B region dead -> h tile; red at K1RED

  float (*red)[8] = (float(*)[8])(lds + K1RED);

  // epilogue: +b1, LayerNorm (cross-wave via red), GELU, Wc dot, h pack
  const float bc0 = bc[0];
  float b1v[8];
  #pragma unroll
  for (int cf = 0; cf < 8; ++cf) b1v[cf] = b1[(cw << 7) + (cf << 4) + l15];

  float ps[2][4], ps2[2][4];
  #pragma unroll
  for (int rf = 0; rf < 2; ++rf)
    #pragma unroll
    for (int r = 0; r < 4; ++r) { ps[rf][r] = 0.f; ps2[rf][r] = 0.f; }

  #pragma unroll
  for (int rf = 0; rf < 2; ++rf)
    #pragma unroll
    for (int cf = 0; cf < 8; ++cf)
      #pragma unroll
      for (int r = 0; r < 4; ++r) {
        const float v = acc[rf][cf][r] + b1v[cf];
        acc[rf][cf][r] = v;
        ps[rf][r] += v; ps2[rf][r] += v * v;
      }
  #pragma unroll
  for (int rf = 0; rf < 2; ++rf)
    #pragma unroll
    for (int r = 0; r < 4; ++r)
      #pragma unroll
      for (int s = 1; s < 16; s <<= 1) {
        ps[rf][r]  += __shfl_xor(ps[rf][r],  s, 64);
        ps2[rf][r] += __shfl_xor(ps2[rf][r], s, 64);
      }
  if (l15 == 0) {
    #pragma unroll
    for (int rf = 0; rf < 2; ++rf)
      #pragma unroll
      for (int r = 0; r < 4; ++r) {
        const int rowb = (rg << 5) + (rf << 4) + (lhi << 2) + r;
        red[rowb][cw << 1]       = ps[rf][r];
        red[rowb][(cw << 1) + 1] = ps2[rf][r];
      }
  }
  __syncthreads();

  float mu[2][4], inv[2][4];
  #pragma unroll
  for (int rf = 0; rf < 2; ++rf)
    #pragma unroll
    for (int r = 0; r < 4; ++r) {
      const int rowb = (rg << 5) + (rf << 4) + (lhi << 2) + r;
      const float s = red[rowb][0] + red[rowb][2];
      const float q = red[rowb][1] + red[rowb][3];
      const float m = s * (1.f / 256.f);
      const float var = q * (1.f / 256.f) - m * m;
      mu[rf][r] = m;
      inv[rf][r] = rsqrtf(var + 1e-5f);
    }

  float gv[8], bv[8], wcv[8];
  #pragma unroll
  for (int cf = 0; cf < 8; ++cf) {
    const int col = (cw << 7) + (cf << 4) + l15;
    gv[cf] = ln_g[col]; bv[cf] = ln_b[col]; wcv[cf] = Wc[col];
  }
  float sc[2][4];
  #pragma unroll
  for (int rf = 0; rf < 2; ++rf)
    #pragma unroll
    for (int r = 0; r < 4; ++r) sc[rf][r] = 0.f;

  #pragma unroll
  for (int rf = 0; rf < 2; ++rf)
    #pragma unroll
    for (int cf = 0; cf < 8; ++cf)
      #pragma unroll
      for (int r = 0; r < 4; ++r) {
        float v = (acc[rf][cf][r] - mu[rf][r]) * inv[rf][r] * gv[cf] + bv[cf];
        v = 0.5f * v * (1.f + erff(v * 0.70710678118654752f));   // exact GELU
        sc[rf][r] += v * wcv[cf];
        const int rowb = (rg << 5) + (rf << 4) + (lhi << 2) + r;
        const int col  = (cw << 7) + (cf << 4) + l15;
        *(__bf16*)(lds + K1H + rowb * 512 + (((col >> 3) ^ (rowb & 7)) << 4)
                   + ((col & 7) << 1)) = (__bf16)v;
      }
  #pragma unroll
  for (int rf = 0; rf < 2; ++rf)
    #pragma unroll
    for (int r = 0; r < 4; ++r)
      #pragma unroll
      for (int s = 1; s < 16; s <<= 1)
        sc[rf][r] += __shfl_xor(sc[rf][r], s, 64);
  if (l15 == 0) {
    #pragma unroll
    for (int rf = 0; rf < 2; ++rf)
      #pragma unroll
      for (int r = 0; r < 4; ++r) {
        const int rowb = (rg << 5) + (rf << 4) + (lhi << 2) + r;
        red[rowb][4 + cw] = sc[rf][r];
      }
  }
  __syncthreads();
  if (tid < 64)
    scores_out[(size_t)bb * Nn + n0 + tid] = red[tid][4] + red[tid][5] + bc0;

  // h tile -> global (un-swizzled, coalesced 16B/lane stores)
  #pragma unroll
  for (int j = 0; j < 8; ++j) {
    const int g   = (j << 8) + tid;      // 0..2047 slots
    const int row = g >> 5;
    const int c   = g & 31;
    const bf16x8 hv = *(const bf16x8*)(lds + K1H + row * 512 +
                                       ((c ^ (row & 7)) << 4));
    *(bf16x8*)(h_out + (size_t)(gr0 + row) * 256 + (c << 3)) = hv;
  }
}

// ---------------- kernel 2: stage2 attention MLP: h @ Wa1^T -> tanh -> Wa2 ---
// grid 256 x 512 thr (8 waves). Per wave 16 rows, K=256, N=128. Wa1 in LDS.
__global__ __launch_bounds__(512) void stage2_kernel(
    const unsigned short* __restrict__ h_in,
    const unsigned short* __restrict__ wa1p,
    const float* __restrict__ ba1,
    const float* __restrict__ Wa2,
    const float* __restrict__ ba2,
    float* __restrict__ logits_out)
{
  __shared__ __align__(16) char lds2[65536];

  const int tid  = threadIdx.x;
  const int wv   = tid >> 6;
  const int lane = tid & 63;
  const int l15  = lane & 15;
  const int lhi  = lane >> 4;

  const int gr0 = blockIdx.x << 7;
  const int bb  = gr0 >> 11;
  const int n0  = gr0 & (Nn - 1);

  // stage Wa1 image (contiguous both sides)
  {
    uint4v st[8];
    #pragma unroll
    for (int j = 0; j < 8; ++j)
      st[j] = *(const uint4v*)(wa1p + (size_t)((j << 9) + tid) * 8);
    #pragma unroll
    for (int j = 0; j < 8; ++j)
      *(uint4v*)(lds2 + ((j << 9) + tid) * 16) = st[j];
  }
  __syncthreads();

  f32x4 acc2[8];
  #pragma unroll
  for (int cf = 0; cf < 8; ++cf) acc2[cf] = (f32x4){0.f, 0.f, 0.f, 0.f};

  const unsigned short* hrow = h_in + (size_t)(gr0 + (wv << 4) + l15) * 256 + (lhi << 3);
  #pragma unroll
  for (int ks = 0; ks < 8; ++ks) {
    const bf16x8 af = *(const bf16x8*)(hrow + (ks << 5));
    #pragma unroll
    for (int cf = 0; cf < 8; ++cf) {
      const int row2 = (cf << 4) + l15;
      const bf16x8 bfr = *(const bf16x8*)(lds2 + row2 * 512 +
                          ((((ks << 2) + lhi) ^ (row2 & 7)) << 4));
      acc2[cf] = __builtin_amdgcn_mfma_f32_16x16x32_bf16(af, bfr, acc2[cf], 0, 0, 0);
    }
  }
  const float ba20 = ba2[0];
  float lg[4] = {0.f, 0.f, 0.f, 0.f};
  #pragma unroll
  for (int cf = 0; cf < 8; ++cf) {
    const int col = (cf << 4) + l15;
    const float bav = ba1[col], w2v = Wa2[col];
    #pragma unroll
    for (int r = 0; r < 4; ++r) {
      const float t = acc2[cf][r] + bav;
      const float e = __expf(2.f * t);
      const float th = 1.f - 2.f / (e + 1.f);
      lg[r] += th * w2v;
    }
  }
  #pragma unroll
  for (int r = 0; r < 4; ++r)
    #pragma unroll
    for (int s = 1; s < 16; s <<= 1) lg[r] += __shfl_xor(lg[r], s, 64);
  if (l15 == 0) {
    #pragma unroll
    for (int r = 0; r < 4; ++r)
      logits_out[(size_t)bb * Nn + n0 + (wv << 4) + (lhi << 2) + r] = lg[r] + ba20;
  }
}

// ---------------- kernel 3: per-batch softmax pooling + dynamic top-k --------
__global__ __launch_bounds__(256) void finalize_kernel(
    const int* __restrict__ lengths,
    const float* __restrict__ scores,
    const float* __restrict__ logits,
    float* __restrict__ video)
{
  const int b = blockIdx.x;
  const int tid = threadIdx.x;
  __shared__ float sS[Nn];
  __shared__ float sL[Nn];
  __shared__ unsigned skey[Nn];
  __shared__ float sred[8];

  const int T = lengths[b];
  for (int i = tid; i < Nn; i += 256) {
    sS[i] = scores[(size_t)b * Nn + i];
    sL[i] = logits[(size_t)b * Nn + i];
  }
  __syncthreads();
  if (T <= 0) { if (tid == 0) video[b] = 0.f; return; }

  float m = -3.0e38f;
  for (int i = tid; i < T; i += 256) m = fmaxf(m, sL[i]);
  #pragma unroll
  for (int s = 1; s < 64; s <<= 1) m = fmaxf(m, __shfl_xor(m, s, 64));
  if ((tid & 63) == 0) sred[tid >> 6] = m;
  __syncthreads();
  m = fmaxf(fmaxf(sred[0], sred[1]), fmaxf(sred[2], sred[3]));
  __syncthreads();

  float se = 0.f, swe = 0.f;
  for (int i = tid; i < T; i += 256) {
    const float e = expf(sL[i] - m);
    se += e; swe += e * sS[i];
  }
  #pragma unroll
  for (int s = 1; s < 64; s <<= 1) { se += __shfl_xor(se, s, 64); swe += __shfl_xor(swe, s, 64); }
  if ((tid & 63) == 0) { sred[tid >> 6] = se; sred[4 + (tid >> 6)] = swe; }
  __syncthreads();
  se  = sred[0] + sred[1] + sred[2] + sred[3];
  swe = sred[4] + sred[5] + sred[6] + sred[7];
  __syncthreads();
  const float attn = swe / se;

  for (int i = tid; i < T; i += 256) {
    const unsigned u = __float_as_uint(sS[i]);
    skey[i] = (u & 0x80000000u) ? ~u : (u | 0x80000000u);
  }
  __syncthreads();
  const int k = max(1, T / 10);
  unsigned ans = 0u;
  for (int bit = 31; bit >= 0; --bit) {
    const unsigned cand = ans | (1u << bit);
    int c = 0;
    for (int i = tid; i < T; i += 256) c += (skey[i] >= cand) ? 1 : 0;
    #pragma unroll
    for (int s = 1; s < 64; s <<= 1) c += __shfl_xor(c, s, 64);
    if ((tid & 63) == 0) sred[tid >> 6] = (float)c;
    __syncthreads();
    c = (int)(sred[0] + sred[1] + sred[2] + sred[3]);
    __syncthreads();
    if (c >= k) ans = cand;
  }
  int cgt = 0; float sgt = 0.f;
  for (int i = tid; i < T; i += 256) {
    if (skey[i] > ans) { cgt++; sgt += sS[i]; }
  }
  #pragma unroll
  for (int s = 1; s < 64; s <<= 1) { cgt += __shfl_xor(cgt, s, 64); sgt += __shfl_xor(sgt, s, 64); }
  if ((tid & 63) == 0) { sred[tid >> 6] = (float)cgt; sred[4 + (tid >> 6)] = sgt; }
  __syncthreads();
  cgt = (int)(sred[0] + sred[1] + sred[2] + sred[3]);
  sgt = sred[4] + sred[5] + sred[6] + sred[7];

  const unsigned ub = (ans & 0x80000000u) ? (ans ^ 0x80000000u) : ~ans;
  const float kth = __uint_as_float(ub);
  const float topk = (sgt + (float)(k - cgt) * kth) / (float)k;
  if (tid == 0) video[b] = 0.5f * attn + 0.5f * topk;
}

extern "C" void kernel_launch(void* const* d_in, const int* in_sizes, int n_in,
                              void* d_out, int out_size, void* d_ws, size_t ws_size,
                              hipStream_t stream) {
  const float* x    = (const float*)d_in[0];
  const int*   len  = (const int*)  d_in[1];
  const float* W1   = (const float*)d_in[2];
  const float* b1   = (const float*)d_in[3];
  const float* ln_g = (const float*)d_in[4];
  const float* ln_b = (const float*)d_in[5];
  const float* Wa1  = (const float*)d_in[6];
  const float* ba1  = (const float*)d_in[7];
  const float* Wa2  = (const float*)d_in[8];
  const float* ba2  = (const float*)d_in[9];
  const float* Wc   = (const float*)d_in[10];
  const float* bc   = (const float*)d_in[11];

  float* out    = (float*)d_out;
  float* video  = out;
  float* scores = out + Bn;

  char* ws = (char*)d_ws;
  float*          logits = (float*)ws;                                 // 128 KB
  unsigned short* h_g    = (unsigned short*)(ws + 131072);             // 16 MB
  unsigned short* w1p    = (unsigned short*)(ws + 131072 + 16777216);  // 512 KB
  unsigned short* wa1p   = (unsigned short*)(ws + 131072 + 16777216 + 524288); // 64 KB

  hipLaunchKernelGGL(pack_weights, dim3(144), dim3(256), 0, stream, W1, Wa1, w1p, wa1p);
  hipLaunchKernelGGL(gemm_ln_kernel, dim3(Bn * Nn / 64), dim3(256), 0, stream,
                     x, b1, ln_g, ln_b, Wc, bc, w1p, scores, h_g);
  hipLaunchKernelGGL(stage2_kernel, dim3(Bn * Nn / 128), dim3(512), 0, stream,
                     h_g, wa1p, ba1, Wa2, ba2, logits);
  hipLaunchKernelGGL(finalize_kernel, dim3(Bn), dim3(256), 0, stream, len, scores, logits, video);
}